// Round 1
// baseline (2726.717 us; speedup 1.0000x reference)
//
#include <hip/hip_runtime.h>
#include <math.h>

#define NL 12

struct LCfg { int ci, co, k, pool; };

struct WQArgs {
  const float* in[40];
  float* out[40];
  int n[40];
};

// power-of-two scale: 2^ceil(log2(max(maxv,1e-8)/levels))
// ratio computed in f32 (matches JAX); log2/ceil in double so ceil lands on the
// mathematically correct side of integer boundaries; exp2 of integer is exact.
__device__ inline float p2_scale_f(float maxv, float levels) {
  float r = __fdiv_rn(fmaxf(maxv, 1e-8f), levels);
  return (float)exp2(ceil(log2((double)r)));
}

// blockDim must be 256. Result valid on thread 0.
__device__ inline float block_reduce_max256(float v) {
  __shared__ float sm[4];
  #pragma unroll
  for (int off = 32; off; off >>= 1) v = fmaxf(v, __shfl_down(v, off));
  if ((threadIdx.x & 63) == 0) sm[threadIdx.x >> 6] = v;
  __syncthreads();
  if (threadIdx.x == 0) v = fmaxf(fmaxf(sm[0], sm[1]), fmaxf(sm[2], sm[3]));
  return v;
}

// v >= 0; non-negative float bits compare like unsigned. Read-then-atomic to
// avoid serializing thousands of atomics on one address.
__device__ inline void slot_max_update(float* slot, float v) {
  volatile unsigned int* su = (volatile unsigned int*)slot;
  unsigned int bits = __float_as_uint(v);
  if (bits > *su) atomicMax((unsigned int*)slot, bits);
}

// One block per tensor: signed fixed-point fake quant (n=127, clip [-128,127]).
__global__ void quant_weights_kernel(WQArgs a) {
  __shared__ float ssc;
  int t = blockIdx.x;
  const float* in = a.in[t];
  float* out = a.out[t];
  int n = a.n[t];
  float m = 0.f;
  for (int i = threadIdx.x; i < n; i += 256) m = fmaxf(m, fabsf(in[i]));
  float bm = block_reduce_max256(m);
  if (threadIdx.x == 0) ssc = p2_scale_f(bm, 127.0f);
  __syncthreads();
  float s = ssc;
  for (int i = threadIdx.x; i < n; i += 256) {
    float q = rintf(__fdiv_rn(in[i], s));   // rintf = round-half-even = jnp.round
    q = fminf(fmaxf(q, -128.f), 127.f);
    out[i] = __fmul_rn(q, s);
  }
}

__global__ void reduce_max_kernel(const float* __restrict__ in, int n, float* slot) {
  float m = 0.f;
  for (int i = blockIdx.x * 256 + threadIdx.x; i < n; i += gridDim.x * 256)
    m = fmaxf(m, in[i]);
  float bm = block_reduce_max256(m);
  if (threadIdx.x == 0) slot_max_update(slot, bm);
}

// unsigned fake quant (levels=255), scale from slot max. in==out allowed.
__global__ void quant_uint_kernel(const float* __restrict__ in, float* __restrict__ out,
                                  int n, const float* __restrict__ slot) {
  __shared__ float ssc;
  if (threadIdx.x == 0) ssc = p2_scale_f(slot[0], 255.0f);
  __syncthreads();
  int i = blockIdx.x * 256 + threadIdx.x;
  if (i >= n) return;
  float s = ssc;
  float q = rintf(__fdiv_rn(in[i], s));
  q = fminf(fmaxf(q, 0.f), 255.f);
  out[i] = __fmul_rn(q, s);
}

// Direct conv + per-channel affine (mul-then-add, NO fma: matches XLA) + ReLU,
// optionally fused 2x2 max-pool (quant is monotone so pool-before-quant is exact),
// and global-max update for the following quantize pass.
// Integer-exactness: inputs are q*2^e (q<=255), weights i*2^f (|i|<=128);
// every partial sum < 2^24 units -> f32 accumulation exact in any order.
template <int K, bool POOL>
__global__ void conv_kernel(const float* __restrict__ in, const float* __restrict__ wq,
                            const float* __restrict__ sg, const float* __restrict__ sb,
                            float* __restrict__ out, float* slot,
                            int N, int Ci, int H, int W, int Co) {
  const int HO = POOL ? (H >> 1) : H;
  const int WO = POOL ? (W >> 1) : W;
  const int total = N * Co * HO * WO;
  const int idx = blockIdx.x * 256 + threadIdx.x;
  float z = 0.f;
  if (idx < total) {
    int wo = idx % WO;
    int t = idx / WO;
    int ho = t % HO; t /= HO;
    int co = t % Co;
    int n  = t / Co;
    const float* wb = wq + (size_t)co * Ci * K * K;
    const float* ib = in + (size_t)n * Ci * H * W;
    float g = sg[co], bb = sb[co];
    float best = 0.f;
    const int NP = POOL ? 2 : 1;
    for (int dy = 0; dy < NP; dy++) {
      for (int dx = 0; dx < NP; dx++) {
        int h = POOL ? 2 * ho + dy : ho;
        int w = POOL ? 2 * wo + dx : wo;
        float acc = 0.f;
        for (int ci = 0; ci < Ci; ci++) {
          const float* ip = ib + (size_t)ci * H * W;
          const float* wp = wb + ci * K * K;
          if (K == 1) {
            acc += ip[h * W + w] * wp[0];
          } else {
            #pragma unroll
            for (int kh = 0; kh < 3; kh++) {
              int ih = h + kh - 1;
              if (ih < 0 || ih >= H) continue;
              #pragma unroll
              for (int kw = 0; kw < 3; kw++) {
                int iw = w + kw - 1;
                if (iw < 0 || iw >= W) continue;
                acc += ip[ih * W + iw] * wp[kh * 3 + kw];
              }
            }
          }
        }
        float zz = fmaxf(__fadd_rn(__fmul_rn(acc, g), bb), 0.f);
        best = fmaxf(best, zz);
      }
    }
    out[idx] = best;
    z = best;
  }
  float bm = block_reduce_max256(z);
  if (threadIdx.x == 0) slot_max_update(slot, bm);
}

// one block per (n,c); mean over HW (sum is integer-exact, divide rounds once)
__global__ void avgpool_kernel(const float* __restrict__ in, float* __restrict__ out,
                               float* slot, int HW) {
  const float* p = in + (size_t)blockIdx.x * HW;
  float s = 0.f;
  for (int i = threadIdx.x; i < HW; i += 256) s += p[i];
  __shared__ float sm[4];
  #pragma unroll
  for (int off = 32; off; off >>= 1) s += __shfl_down(s, off);
  if ((threadIdx.x & 63) == 0) sm[threadIdx.x >> 6] = s;
  __syncthreads();
  if (threadIdx.x == 0) {
    float tot = (sm[0] + sm[1]) + (sm[2] + sm[3]);
    float m = __fdiv_rn(tot, (float)HW);
    out[blockIdx.x] = m;
    slot_max_update(slot, m);
  }
}

// x[16,64] @ w[16,64]^T + b, relu, track max. 256 threads = all outputs.
__global__ void fc1_kernel(const float* __restrict__ x, const float* __restrict__ w,
                           const float* __restrict__ b, float* __restrict__ out,
                           float* slot) {
  int i = threadIdx.x;
  int n = i >> 4, j = i & 15;
  float acc = 0.f;
  for (int k = 0; k < 64; k++) acc += x[n * 64 + k] * w[j * 64 + k];  // exact
  float z = fmaxf(__fadd_rn(acc, b[j]), 0.f);
  out[i] = z;
  float bm = block_reduce_max256(z);
  if (threadIdx.x == 0) slot_max_update(slot, bm);
}

// x[16,16] @ w[10,16]^T + b -> d_out[16,10]
__global__ void fc2_kernel(const float* __restrict__ x, const float* __restrict__ w,
                           const float* __restrict__ b, float* __restrict__ out) {
  int i = blockIdx.x * 256 + threadIdx.x;
  if (i < 160) {
    int n = i / 10, j = i % 10;
    float acc = 0.f;
    for (int k = 0; k < 16; k++) acc += x[n * 16 + k] * w[j * 16 + k];  // exact
    out[i] = __fadd_rn(acc, b[j]);
  }
}

extern "C" void kernel_launch(void* const* d_in, const int* in_sizes, int n_in,
                              void* d_out, int out_size, void* d_ws, size_t ws_size,
                              hipStream_t stream) {
  static const LCfg cfg[NL] = {
    {3, 32, 3, 1}, {32, 16, 3, 1}, {16, 16, 1, 0}, {16, 32, 3, 0},
    {32, 32, 1, 0}, {32, 64, 3, 1}, {64, 32, 1, 0}, {32, 64, 3, 0},
    {64, 32, 1, 0}, {32, 64, 3, 0}, {64, 32, 1, 0}, {32, 64, 3, 0}};

  float* ws = (float*)d_ws;
  float* slots = ws;                 // slots[0..15]: max-reduction scratch
  size_t off = 32;

  float* wq[NL]; float* sgq[NL]; float* sbq[NL];
  for (int l = 0; l < NL; l++) {
    int n = cfg[l].co * cfg[l].ci * cfg[l].k * cfg[l].k;
    wq[l] = ws + off; off += (size_t)((n + 15) & ~15);
  }
  for (int l = 0; l < NL; l++) { sgq[l] = ws + off; off += 64; }
  for (int l = 0; l < NL; l++) { sbq[l] = ws + off; off += 64; }
  float* fw1q = ws + off; off += 1024;
  float* fb1q = ws + off; off += 16;
  float* fw2q = ws + off; off += 160;
  float* fb2q = ws + off; off += 16;
  // ping-pong activations: A holds qin (2.41M) and odd-stage outputs,
  // B holds conv1 pooled output (6.42M max) and even-stage outputs.
  float* A = ws + off; off += 2408448;
  float* B = ws + off; off += 6422528;  // total ws use ~36 MB

  WQArgs wa;
  for (int l = 0; l < NL; l++) {
    wa.in[l]      = (const float*)d_in[1 + 3 * l]; wa.out[l]      = wq[l];
    wa.n[l]       = cfg[l].co * cfg[l].ci * cfg[l].k * cfg[l].k;
    wa.in[12 + l] = (const float*)d_in[2 + 3 * l]; wa.out[12 + l] = sgq[l];
    wa.n[12 + l]  = cfg[l].co;
    wa.in[24 + l] = (const float*)d_in[3 + 3 * l]; wa.out[24 + l] = sbq[l];
    wa.n[24 + l]  = cfg[l].co;
  }
  wa.in[36] = (const float*)d_in[37]; wa.out[36] = fw1q; wa.n[36] = 1024;
  wa.in[37] = (const float*)d_in[38]; wa.out[37] = fb1q; wa.n[37] = 16;
  wa.in[38] = (const float*)d_in[39]; wa.out[38] = fw2q; wa.n[38] = 160;
  wa.in[39] = (const float*)d_in[40]; wa.out[39] = fb2q; wa.n[39] = 10;

  hipMemsetAsync(slots, 0, 32 * sizeof(float), stream);
  quant_weights_kernel<<<40, 256, 0, stream>>>(wa);

  const float* x = (const float*)d_in[0];
  const int nx = 16 * 3 * 224 * 224;
  reduce_max_kernel<<<(nx + 255) / 256, 256, 0, stream>>>(x, nx, slots + 0);
  quant_uint_kernel<<<(nx + 255) / 256, 256, 0, stream>>>(x, A, nx, slots + 0);

  float* cur = A;
  float* nxt = B;
  int H = 224;
  for (int l = 0; l < NL; l++) {
    int Ci = cfg[l].ci, Co = cfg[l].co, K = cfg[l].k, P = cfg[l].pool;
    int HO = P ? H / 2 : H;
    int total = 16 * Co * HO * HO;
    int blocks = (total + 255) / 256;
    if (K == 3 && P)
      conv_kernel<3, true><<<blocks, 256, 0, stream>>>(
          cur, wq[l], sgq[l], sbq[l], nxt, slots + 1 + l, 16, Ci, H, H, Co);
    else if (K == 3)
      conv_kernel<3, false><<<blocks, 256, 0, stream>>>(
          cur, wq[l], sgq[l], sbq[l], nxt, slots + 1 + l, 16, Ci, H, H, Co);
    else
      conv_kernel<1, false><<<blocks, 256, 0, stream>>>(
          cur, wq[l], sgq[l], sbq[l], nxt, slots + 1 + l, 16, Ci, H, H, Co);
    quant_uint_kernel<<<blocks, 256, 0, stream>>>(nxt, nxt, total, slots + 1 + l);
    float* t = cur; cur = nxt; nxt = t;
    H = HO;
  }
  // cur == A: quantized [16,64,28,28]
  avgpool_kernel<<<16 * 64, 256, 0, stream>>>(cur, nxt, slots + 13, 28 * 28);
  quant_uint_kernel<<<4, 256, 0, stream>>>(nxt, nxt, 1024, slots + 13);
  fc1_kernel<<<1, 256, 0, stream>>>(nxt, fw1q, fb1q, cur, slots + 14);
  quant_uint_kernel<<<1, 256, 0, stream>>>(cur, cur, 256, slots + 14);
  fc2_kernel<<<1, 256, 0, stream>>>(cur, fw2q, fb2q, (float*)d_out);
}

// Round 2
// 609.865 us; speedup vs baseline: 4.4710x; 4.4710x over previous
//
#include <hip/hip_runtime.h>
#include <math.h>

#define NL 12

struct LCfg { int ci, co, k, pool; };

struct WQArgs {
  const float* in[40];
  float* out[40];
  int n[40];
  int tc[40];   // >0: write transposed as [n/tc][tc] (tc = out-channel count)
};

// power-of-two scale: 2^ceil(log2(max(maxv,1e-8)/levels))
__device__ inline float p2_scale_f(float maxv, float levels) {
  float r = __fdiv_rn(fmaxf(maxv, 1e-8f), levels);
  return (float)exp2(ceil(log2((double)r)));
}

// blockDim must be 256. Result valid on thread 0. All threads must reach.
__device__ inline float block_reduce_max256(float v) {
  __shared__ float sm[4];
  #pragma unroll
  for (int off = 32; off; off >>= 1) v = fmaxf(v, __shfl_down(v, off));
  if ((threadIdx.x & 63) == 0) sm[threadIdx.x >> 6] = v;
  __syncthreads();
  if (threadIdx.x == 0) v = fmaxf(fmaxf(sm[0], sm[1]), fmaxf(sm[2], sm[3]));
  return v;
}

// v >= 0; non-negative float bits compare like unsigned.
__device__ inline void slot_max_update(float* slot, float v) {
  volatile unsigned int* su = (volatile unsigned int*)slot;
  unsigned int bits = __float_as_uint(v);
  if (bits > *su) atomicMax((unsigned int*)slot, bits);
}

// One block per tensor: signed fixed-point fake quant (n=127, clip [-128,127]).
// tc>0: output transposed to [nw][tc] so conv/fc weight reads are channel-minor.
__global__ void quant_weights_kernel(WQArgs a) {
  __shared__ float ssc;
  int t = blockIdx.x;
  const float* in = a.in[t];
  float* out = a.out[t];
  int n = a.n[t], tc = a.tc[t];
  float m = 0.f;
  for (int i = threadIdx.x; i < n; i += 256) m = fmaxf(m, fabsf(in[i]));
  float bm = block_reduce_max256(m);
  if (threadIdx.x == 0) ssc = p2_scale_f(bm, 127.0f);
  __syncthreads();
  float s = ssc;
  int nw = tc > 0 ? n / tc : 1;
  for (int i = threadIdx.x; i < n; i += 256) {
    float q = rintf(__fdiv_rn(in[i], s));   // round-half-even = jnp.round
    q = fminf(fmaxf(q, -128.f), 127.f);
    float v = __fmul_rn(q, s);
    if (tc > 0) out[(i % nw) * tc + i / nw] = v;
    else out[i] = v;
  }
}

__global__ void reduce_max_kernel(const float* __restrict__ in, int n, float* slot) {
  float m = 0.f;
  for (int i = blockIdx.x * 256 + threadIdx.x; i < n; i += gridDim.x * 256)
    m = fmaxf(m, in[i]);
  float bm = block_reduce_max256(m);
  if (threadIdx.x == 0) slot_max_update(slot, bm);
}

// unsigned fake quant (levels=255), scale from slot max. in==out allowed.
__global__ void quant_uint_kernel(const float* __restrict__ in, float* __restrict__ out,
                                  int n, const float* __restrict__ slot) {
  __shared__ float ssc;
  if (threadIdx.x == 0) ssc = p2_scale_f(slot[0], 255.0f);
  __syncthreads();
  int i = blockIdx.x * 256 + threadIdx.x;
  if (i >= n) return;
  float s = ssc;
  float q = rintf(__fdiv_rn(in[i], s));
  q = fminf(fmaxf(q, 0.f), 255.f);
  out[i] = __fmul_rn(q, s);
}

// ---- register-blocked direct convs ----
// COB output channels per thread; weights transposed [ci*k*k][Co] so weight
// addresses are block-uniform -> scalar loads (constant cache, no VALU).
// Inner FMA contraction is exact here (all values q*2^e, sums < 2^24 units).
// Affine epilogue stays mul-then-add (no FMA) to match XLA.

template <int COB>
__global__ __launch_bounds__(256, 4)
void conv3x3_pool_kernel(const float* __restrict__ in, const float* __restrict__ wt,
                         const float* __restrict__ sg, const float* __restrict__ sb,
                         float* __restrict__ out, float* slot,
                         int Ci, int H, int Co) {
  const int W = H;
  const int HO = H >> 1, WO = W >> 1;
  const int CoG = Co / COB;
  const int cg = blockIdx.y % CoG;
  const int n  = blockIdx.y / CoG;
  const int sp = blockIdx.x * 256 + threadIdx.x;
  float zmax = 0.f;
  if (sp < HO * WO) {
    const int wo = sp % WO, ho = sp / WO;
    const int hb = 2 * ho - 1, wb = 2 * wo - 1;
    int ro[4], cw[4]; float rm[4], cm[4];
    #pragma unroll
    for (int r = 0; r < 4; r++) {
      int ih = hb + r;
      rm[r] = (ih >= 0 && ih < H) ? 1.f : 0.f;
      ro[r] = min(max(ih, 0), H - 1) * W;
      int iw = wb + r;
      cm[r] = (iw >= 0 && iw < W) ? 1.f : 0.f;
      cw[r] = min(max(iw, 0), W - 1);
    }
    int off[4][4]; float msk[4][4];
    #pragma unroll
    for (int r = 0; r < 4; r++)
      #pragma unroll
      for (int c = 0; c < 4; c++) { off[r][c] = ro[r] + cw[c]; msk[r][c] = rm[r] * cm[c]; }

    const float* ib = in + n * Ci * H * W;
    const float* wbase = wt + cg * COB;
    float acc[4][COB];
    #pragma unroll
    for (int p = 0; p < 4; p++)
      #pragma unroll
      for (int c = 0; c < COB; c++) acc[p][c] = 0.f;

    for (int ci = 0; ci < Ci; ci++) {
      const float* ip = ib + ci * H * W;
      float p[4][4];
      #pragma unroll
      for (int r = 0; r < 4; r++)
        #pragma unroll
        for (int c = 0; c < 4; c++) p[r][c] = ip[off[r][c]] * msk[r][c];
      #pragma unroll
      for (int kh = 0; kh < 3; kh++) {
        #pragma unroll
        for (int kw = 0; kw < 3; kw++) {
          const float* wp = wbase + (ci * 9 + kh * 3 + kw) * Co;  // uniform -> s_load
          #pragma unroll
          for (int c = 0; c < COB; c++) {
            float wv = wp[c];
            acc[0][c] += p[kh][kw]         * wv;
            acc[1][c] += p[kh][kw + 1]     * wv;
            acc[2][c] += p[kh + 1][kw]     * wv;
            acc[3][c] += p[kh + 1][kw + 1] * wv;
          }
        }
      }
    }
    #pragma unroll
    for (int c = 0; c < COB; c++) {
      float g = sg[cg * COB + c], bb = sb[cg * COB + c];
      float best = 0.f;
      #pragma unroll
      for (int p = 0; p < 4; p++)
        best = fmaxf(best, fmaxf(__fadd_rn(__fmul_rn(acc[p][c], g), bb), 0.f));
      out[((n * Co + cg * COB + c) * HO + ho) * WO + wo] = best;
      zmax = fmaxf(zmax, best);
    }
  }
  float bm = block_reduce_max256(zmax);
  if (threadIdx.x == 0) slot_max_update(slot, bm);
}

template <int COB>
__global__ __launch_bounds__(256, 4)
void conv3x3_kernel(const float* __restrict__ in, const float* __restrict__ wt,
                    const float* __restrict__ sg, const float* __restrict__ sb,
                    float* __restrict__ out, float* slot,
                    int Ci, int H, int Co) {
  const int W = H;
  const int CoG = Co / COB;
  const int cg = blockIdx.y % CoG;
  const int n  = blockIdx.y / CoG;
  const int sp = blockIdx.x * 256 + threadIdx.x;
  float zmax = 0.f;
  if (sp < H * W) {
    const int wo = sp % W, ho = sp / W;
    int off[3][3]; float msk[3][3];
    #pragma unroll
    for (int r = 0; r < 3; r++) {
      int ih = ho + r - 1;
      float rmv = (ih >= 0 && ih < H) ? 1.f : 0.f;
      int rov = min(max(ih, 0), H - 1) * W;
      #pragma unroll
      for (int c = 0; c < 3; c++) {
        int iw = wo + c - 1;
        msk[r][c] = ((iw >= 0 && iw < W) ? 1.f : 0.f) * rmv;
        off[r][c] = rov + min(max(iw, 0), W - 1);
      }
    }
    const float* ib = in + n * Ci * H * W;
    const float* wbase = wt + cg * COB;
    float acc[COB];
    #pragma unroll
    for (int c = 0; c < COB; c++) acc[c] = 0.f;

    for (int ci = 0; ci < Ci; ci++) {
      const float* ip = ib + ci * H * W;
      float p[3][3];
      #pragma unroll
      for (int r = 0; r < 3; r++)
        #pragma unroll
        for (int c = 0; c < 3; c++) p[r][c] = ip[off[r][c]] * msk[r][c];
      #pragma unroll
      for (int kh = 0; kh < 3; kh++)
        #pragma unroll
        for (int kw = 0; kw < 3; kw++) {
          const float* wp = wbase + (ci * 9 + kh * 3 + kw) * Co;  // uniform -> s_load
          #pragma unroll
          for (int c = 0; c < COB; c++) acc[c] += p[kh][kw] * wp[c];
        }
    }
    #pragma unroll
    for (int c = 0; c < COB; c++) {
      float g = sg[cg * COB + c], bb = sb[cg * COB + c];
      float z = fmaxf(__fadd_rn(__fmul_rn(acc[c], g), bb), 0.f);
      out[((n * Co + cg * COB + c) * H + ho) * W + wo] = z;
      zmax = fmaxf(zmax, z);
    }
  }
  float bm = block_reduce_max256(zmax);
  if (threadIdx.x == 0) slot_max_update(slot, bm);
}

template <int COB>
__global__ __launch_bounds__(256, 4)
void conv1x1_kernel(const float* __restrict__ in, const float* __restrict__ wt,
                    const float* __restrict__ sg, const float* __restrict__ sb,
                    float* __restrict__ out, float* slot,
                    int Ci, int H, int Co) {
  const int W = H;
  const int CoG = Co / COB;
  const int cg = blockIdx.y % CoG;
  const int n  = blockIdx.y / CoG;
  const int sp = blockIdx.x * 256 + threadIdx.x;
  float zmax = 0.f;
  if (sp < H * W) {
    const float* ib = in + n * Ci * H * W;
    const float* wbase = wt + cg * COB;
    float acc[COB];
    #pragma unroll
    for (int c = 0; c < COB; c++) acc[c] = 0.f;
    for (int ci = 0; ci < Ci; ci++) {
      float v = ib[ci * H * W + sp];
      const float* wp = wbase + ci * Co;  // uniform -> s_load
      #pragma unroll
      for (int c = 0; c < COB; c++) acc[c] += v * wp[c];
    }
    #pragma unroll
    for (int c = 0; c < COB; c++) {
      float g = sg[cg * COB + c], bb = sb[cg * COB + c];
      float z = fmaxf(__fadd_rn(__fmul_rn(acc[c], g), bb), 0.f);
      out[(n * Co + cg * COB + c) * H * W + sp] = z;
      zmax = fmaxf(zmax, z);
    }
  }
  float bm = block_reduce_max256(zmax);
  if (threadIdx.x == 0) slot_max_update(slot, bm);
}

// one block per (n,c); mean over HW (sum is integer-exact, divide rounds once)
__global__ void avgpool_kernel(const float* __restrict__ in, float* __restrict__ out,
                               float* slot, int HW) {
  const float* p = in + (size_t)blockIdx.x * HW;
  float s = 0.f;
  for (int i = threadIdx.x; i < HW; i += 256) s += p[i];
  __shared__ float sm[4];
  #pragma unroll
  for (int off = 32; off; off >>= 1) s += __shfl_down(s, off);
  if ((threadIdx.x & 63) == 0) sm[threadIdx.x >> 6] = s;
  __syncthreads();
  if (threadIdx.x == 0) {
    float tot = (sm[0] + sm[1]) + (sm[2] + sm[3]);
    float m = __fdiv_rn(tot, (float)HW);
    out[blockIdx.x] = m;
    slot_max_update(slot, m);
  }
}

// x[16,64] @ wT[64,16] + b, relu, track max. wT is transposed fc1 weight.
__global__ void fc1_kernel(const float* __restrict__ x, const float* __restrict__ wt,
                           const float* __restrict__ b, float* __restrict__ out,
                           float* slot) {
  int i = threadIdx.x;
  int n = i >> 4, j = i & 15;
  float acc = 0.f;
  for (int k = 0; k < 64; k++) acc += x[n * 64 + k] * wt[k * 16 + j];  // exact
  float z = fmaxf(__fadd_rn(acc, b[j]), 0.f);
  out[i] = z;
  float bm = block_reduce_max256(z);
  if (threadIdx.x == 0) slot_max_update(slot, bm);
}

// x[16,16] @ wT[16,10] + b -> d_out[16,10]
__global__ void fc2_kernel(const float* __restrict__ x, const float* __restrict__ wt,
                           const float* __restrict__ b, float* __restrict__ out) {
  int i = blockIdx.x * 256 + threadIdx.x;
  if (i < 160) {
    int n = i / 10, j = i % 10;
    float acc = 0.f;
    for (int k = 0; k < 16; k++) acc += x[n * 16 + k] * wt[k * 10 + j];  // exact
    out[i] = __fadd_rn(acc, b[j]);
  }
}

extern "C" void kernel_launch(void* const* d_in, const int* in_sizes, int n_in,
                              void* d_out, int out_size, void* d_ws, size_t ws_size,
                              hipStream_t stream) {
  static const LCfg cfg[NL] = {
    {3, 32, 3, 1}, {32, 16, 3, 1}, {16, 16, 1, 0}, {16, 32, 3, 0},
    {32, 32, 1, 0}, {32, 64, 3, 1}, {64, 32, 1, 0}, {32, 64, 3, 0},
    {64, 32, 1, 0}, {32, 64, 3, 0}, {64, 32, 1, 0}, {32, 64, 3, 0}};

  float* ws = (float*)d_ws;
  float* slots = ws;                 // slots[0..15]: max-reduction scratch
  size_t off = 32;

  float* wq[NL]; float* sgq[NL]; float* sbq[NL];
  for (int l = 0; l < NL; l++) {
    int n = cfg[l].co * cfg[l].ci * cfg[l].k * cfg[l].k;
    wq[l] = ws + off; off += (size_t)((n + 15) & ~15);
  }
  for (int l = 0; l < NL; l++) { sgq[l] = ws + off; off += 64; }
  for (int l = 0; l < NL; l++) { sbq[l] = ws + off; off += 64; }
  float* fw1q = ws + off; off += 1024;
  float* fb1q = ws + off; off += 16;
  float* fw2q = ws + off; off += 160;
  float* fb2q = ws + off; off += 16;
  float* A = ws + off; off += 2408448;
  float* B = ws + off; off += 6422528;  // total ws use ~36 MB

  WQArgs wa;
  for (int l = 0; l < NL; l++) {
    wa.in[l]      = (const float*)d_in[1 + 3 * l]; wa.out[l]      = wq[l];
    wa.n[l]       = cfg[l].co * cfg[l].ci * cfg[l].k * cfg[l].k;
    wa.tc[l]      = cfg[l].co;                       // transpose conv weights
    wa.in[12 + l] = (const float*)d_in[2 + 3 * l]; wa.out[12 + l] = sgq[l];
    wa.n[12 + l]  = cfg[l].co;  wa.tc[12 + l] = 0;
    wa.in[24 + l] = (const float*)d_in[3 + 3 * l]; wa.out[24 + l] = sbq[l];
    wa.n[24 + l]  = cfg[l].co;  wa.tc[24 + l] = 0;
  }
  wa.in[36] = (const float*)d_in[37]; wa.out[36] = fw1q; wa.n[36] = 1024; wa.tc[36] = 16;
  wa.in[37] = (const float*)d_in[38]; wa.out[37] = fb1q; wa.n[37] = 16;   wa.tc[37] = 0;
  wa.in[38] = (const float*)d_in[39]; wa.out[38] = fw2q; wa.n[38] = 160;  wa.tc[38] = 10;
  wa.in[39] = (const float*)d_in[40]; wa.out[39] = fb2q; wa.n[39] = 10;   wa.tc[39] = 0;

  hipMemsetAsync(slots, 0, 32 * sizeof(float), stream);
  quant_weights_kernel<<<40, 256, 0, stream>>>(wa);

  const float* x = (const float*)d_in[0];
  const int nx = 16 * 3 * 224 * 224;
  reduce_max_kernel<<<(nx + 255) / 256, 256, 0, stream>>>(x, nx, slots + 0);
  quant_uint_kernel<<<(nx + 255) / 256, 256, 0, stream>>>(x, A, nx, slots + 0);

  float* cur = A;
  float* nxt = B;
  int H = 224;
  for (int l = 0; l < NL; l++) {
    int Ci = cfg[l].ci, Co = cfg[l].co, K = cfg[l].k, P = cfg[l].pool;
    int HO = P ? H / 2 : H;
    int sblocks = (HO * HO + 255) / 256;
    dim3 grid(sblocks, 16 * (Co / 8));
    if (K == 3 && P)
      conv3x3_pool_kernel<8><<<grid, 256, 0, stream>>>(
          cur, wq[l], sgq[l], sbq[l], nxt, slots + 1 + l, Ci, H, Co);
    else if (K == 3)
      conv3x3_kernel<8><<<grid, 256, 0, stream>>>(
          cur, wq[l], sgq[l], sbq[l], nxt, slots + 1 + l, Ci, H, Co);
    else
      conv1x1_kernel<8><<<grid, 256, 0, stream>>>(
          cur, wq[l], sgq[l], sbq[l], nxt, slots + 1 + l, Ci, H, Co);
    int total = 16 * Co * HO * HO;
    quant_uint_kernel<<<(total + 255) / 256, 256, 0, stream>>>(nxt, nxt, total, slots + 1 + l);
    float* t = cur; cur = nxt; nxt = t;
    H = HO;
  }
  // cur: quantized [16,64,28,28]
  avgpool_kernel<<<16 * 64, 256, 0, stream>>>(cur, nxt, slots + 13, 28 * 28);
  quant_uint_kernel<<<4, 256, 0, stream>>>(nxt, nxt, 1024, slots + 13);
  fc1_kernel<<<1, 256, 0, stream>>>(nxt, fw1q, fb1q, cur, slots + 14);
  quant_uint_kernel<<<1, 256, 0, stream>>>(cur, cur, 256, slots + 14);
  fc2_kernel<<<1, 256, 0, stream>>>(cur, fw2q, fb2q, (float*)d_out);
}

// Round 3
// 593.291 us; speedup vs baseline: 4.5959x; 1.0279x over previous
//
#include <hip/hip_runtime.h>
#include <math.h>

#define NL 12

struct WQArgs {
  const float* in[40];
  float* out[40];
  int n[40];
  int tc[40];   // >0: write transposed as [n/tc][tc]
};

// power-of-two scale: 2^ceil(log2(max(maxv,1e-8)/levels)); double log2/ceil so
// ceil lands on the correct side of integer boundaries; exp2(int) exact.
__device__ inline float p2_scale_f(float maxv, float levels) {
  float r = __fdiv_rn(fmaxf(maxv, 1e-8f), levels);
  return (float)exp2(ceil(log2((double)r)));
}

// blockDim must be 256. Result valid on thread 0. All threads must reach.
__device__ inline float block_reduce_max256(float v) {
  __shared__ float sm[4];
  #pragma unroll
  for (int off = 32; off; off >>= 1) v = fmaxf(v, __shfl_down(v, off));
  if ((threadIdx.x & 63) == 0) sm[threadIdx.x >> 6] = v;
  __syncthreads();
  if (threadIdx.x == 0) v = fmaxf(fmaxf(sm[0], sm[1]), fmaxf(sm[2], sm[3]));
  return v;
}

// v >= 0; non-negative float bits compare like unsigned.
__device__ inline void slot_max_update(float* slot, float v) {
  volatile unsigned int* su = (volatile unsigned int*)slot;
  unsigned int bits = __float_as_uint(v);
  if (bits > *su) atomicMax((unsigned int*)slot, bits);
}

// fused activation fake-quant on the load path. s = 2^e so v*inv == v/s exactly;
// post-ReLU activations satisfy 0 <= v/s <= 255 by scale construction -> no clamps.
__device__ inline float qact(float v, float inv, float s) {
  return __fmul_rn(rintf(__fmul_rn(v, inv)), s);
}

// blocks [0,40): per-tensor signed weight fake-quant (n=127, clip [-128,127]),
// optional transpose to channel-minor. blocks >=40: grid-stride max-reduce of x.
__global__ void prep_kernel(WQArgs a, const float* __restrict__ x, int nx, float* slot0) {
  if (blockIdx.x < 40) {
    __shared__ float ssc;
    int t = blockIdx.x;
    const float* in = a.in[t];
    float* out = a.out[t];
    int n = a.n[t], tc = a.tc[t];
    float m = 0.f;
    for (int i = threadIdx.x; i < n; i += 256) m = fmaxf(m, fabsf(in[i]));
    float bm = block_reduce_max256(m);
    if (threadIdx.x == 0) ssc = p2_scale_f(bm, 127.0f);
    __syncthreads();
    float s = ssc;
    int nw = tc > 0 ? n / tc : 1;
    for (int i = threadIdx.x; i < n; i += 256) {
      float q = rintf(__fdiv_rn(in[i], s));   // round-half-even = jnp.round
      q = fminf(fmaxf(q, -128.f), 127.f);
      float v = __fmul_rn(q, s);
      if (tc > 0) out[(i % nw) * tc + i / nw] = v;
      else out[i] = v;
    }
  } else {
    float m = 0.f;
    for (int i = (blockIdx.x - 40) * 256 + threadIdx.x; i < nx;
         i += (gridDim.x - 40) * 256)
      m = fmaxf(m, x[i]);
    float bm = block_reduce_max256(m);
    if (threadIdx.x == 0) slot_max_update(slot0, bm);
  }
}

// ---- register-blocked direct convs, fully templated ----
// Input buffer holds RAW previous-layer output; quantization of the previous
// activation is applied on load (qact). Weights transposed [ci*k*k][Co] so
// weight addresses are wave-uniform -> scalar loads. Inner-dot FMA contraction
// exact (all values q*2^e, sums < 2^24 units). Affine epilogue mul-then-add.

template <int CI, int H, int CO, int COB>
__global__ __launch_bounds__(256, 4)
void conv3x3_pool_t(const float* __restrict__ in, const float* __restrict__ wt,
                    const float* __restrict__ sg, const float* __restrict__ sb,
                    float* __restrict__ out, const float* __restrict__ slot_in,
                    float* slot_out) {
  constexpr int W = H, HO = H / 2, WO = W / 2, SP = HO * WO, NSP = 16 * SP;
  const int cg = blockIdx.y;
  const int spg = blockIdx.x * 256 + threadIdx.x;
  const float s_in = p2_scale_f(slot_in[0], 255.0f);
  const float inv = __fdiv_rn(1.0f, s_in);   // exact: s_in is 2^e
  float zmax = 0.f;
  if (spg < NSP) {
    const int n = spg / SP, sp = spg % SP, ho = sp / WO, wo = sp % WO;
    const int hb = 2 * ho - 1, wb = 2 * wo - 1;
    int ro[4], cw[4]; float rm[4], cm[4];
    #pragma unroll
    for (int r = 0; r < 4; r++) {
      int ih = hb + r;
      rm[r] = (ih >= 0 && ih < H) ? 1.f : 0.f;
      ro[r] = min(max(ih, 0), H - 1) * W;
      int iw = wb + r;
      cm[r] = (iw >= 0 && iw < W) ? 1.f : 0.f;
      cw[r] = min(max(iw, 0), W - 1);
    }
    int off[4][4]; float smk[4][4];  // smk folds s_in * border mask
    #pragma unroll
    for (int r = 0; r < 4; r++)
      #pragma unroll
      for (int c = 0; c < 4; c++) {
        off[r][c] = ro[r] + cw[c];
        smk[r][c] = __fmul_rn(s_in, rm[r] * cm[c]);
      }

    const float* ib = in + n * CI * H * W;
    const float* wb2 = wt + cg * COB;
    float acc[4][COB];
    #pragma unroll
    for (int p = 0; p < 4; p++)
      #pragma unroll
      for (int c = 0; c < COB; c++) acc[p][c] = 0.f;

    #pragma unroll 4
    for (int ci = 0; ci < CI; ci++) {
      const float* ip = ib + ci * H * W;
      float p[4][4];
      #pragma unroll
      for (int r = 0; r < 4; r++)
        #pragma unroll
        for (int c = 0; c < 4; c++)
          p[r][c] = __fmul_rn(rintf(__fmul_rn(ip[off[r][c]], inv)), smk[r][c]);
      #pragma unroll
      for (int kh = 0; kh < 3; kh++)
        #pragma unroll
        for (int kw = 0; kw < 3; kw++) {
          const float* wp = wb2 + (ci * 9 + kh * 3 + kw) * CO;  // uniform -> s_load
          #pragma unroll
          for (int c = 0; c < COB; c++) {
            float wv = wp[c];
            acc[0][c] += p[kh][kw]         * wv;
            acc[1][c] += p[kh][kw + 1]     * wv;
            acc[2][c] += p[kh + 1][kw]     * wv;
            acc[3][c] += p[kh + 1][kw + 1] * wv;
          }
        }
    }
    #pragma unroll
    for (int c = 0; c < COB; c++) {
      float g = sg[cg * COB + c], bb = sb[cg * COB + c];
      float best = 0.f;
      #pragma unroll
      for (int p = 0; p < 4; p++)
        best = fmaxf(best, fmaxf(__fadd_rn(__fmul_rn(acc[p][c], g), bb), 0.f));
      out[((n * CO + cg * COB + c) * HO + ho) * WO + wo] = best;
      zmax = fmaxf(zmax, best);
    }
  }
  float bm = block_reduce_max256(zmax);
  if (threadIdx.x == 0) slot_max_update(slot_out, bm);
}

template <int CI, int H, int CO, int COB>
__global__ __launch_bounds__(256, 4)
void conv3x3_t(const float* __restrict__ in, const float* __restrict__ wt,
               const float* __restrict__ sg, const float* __restrict__ sb,
               float* __restrict__ out, const float* __restrict__ slot_in,
               float* slot_out) {
  constexpr int W = H, SP = H * W, NSP = 16 * SP;
  const int cg = blockIdx.y;
  const int spg = blockIdx.x * 256 + threadIdx.x;
  const float s_in = p2_scale_f(slot_in[0], 255.0f);
  const float inv = __fdiv_rn(1.0f, s_in);
  float zmax = 0.f;
  if (spg < NSP) {
    const int n = spg / SP, sp = spg % SP, ho = sp / W, wo = sp % W;
    int off[3][3]; float smk[3][3];
    #pragma unroll
    for (int r = 0; r < 3; r++) {
      int ih = ho + r - 1;
      float rmv = (ih >= 0 && ih < H) ? 1.f : 0.f;
      int rov = min(max(ih, 0), H - 1) * W;
      #pragma unroll
      for (int c = 0; c < 3; c++) {
        int iw = wo + c - 1;
        smk[r][c] = __fmul_rn(s_in, ((iw >= 0 && iw < W) ? 1.f : 0.f) * rmv);
        off[r][c] = rov + min(max(iw, 0), W - 1);
      }
    }
    const float* ib = in + n * CI * H * W;
    const float* wb2 = wt + cg * COB;
    float acc[COB];
    #pragma unroll
    for (int c = 0; c < COB; c++) acc[c] = 0.f;

    #pragma unroll 4
    for (int ci = 0; ci < CI; ci++) {
      const float* ip = ib + ci * H * W;
      float p[3][3];
      #pragma unroll
      for (int r = 0; r < 3; r++)
        #pragma unroll
        for (int c = 0; c < 3; c++)
          p[r][c] = __fmul_rn(rintf(__fmul_rn(ip[off[r][c]], inv)), smk[r][c]);
      #pragma unroll
      for (int kh = 0; kh < 3; kh++)
        #pragma unroll
        for (int kw = 0; kw < 3; kw++) {
          const float* wp = wb2 + (ci * 9 + kh * 3 + kw) * CO;
          #pragma unroll
          for (int c = 0; c < COB; c++) acc[c] += p[kh][kw] * wp[c];
        }
    }
    #pragma unroll
    for (int c = 0; c < COB; c++) {
      float g = sg[cg * COB + c], bb = sb[cg * COB + c];
      float z = fmaxf(__fadd_rn(__fmul_rn(acc[c], g), bb), 0.f);
      out[((n * CO + cg * COB + c) * H + ho) * W + wo] = z;
      zmax = fmaxf(zmax, z);
    }
  }
  float bm = block_reduce_max256(zmax);
  if (threadIdx.x == 0) slot_max_update(slot_out, bm);
}

template <int CI, int H, int CO, int COB>
__global__ __launch_bounds__(256, 4)
void conv1x1_t(const float* __restrict__ in, const float* __restrict__ wt,
               const float* __restrict__ sg, const float* __restrict__ sb,
               float* __restrict__ out, const float* __restrict__ slot_in,
               float* slot_out) {
  constexpr int W = H, SP = H * W, NSP = 16 * SP;
  const int cg = blockIdx.y;
  const int spg = blockIdx.x * 256 + threadIdx.x;
  const float s_in = p2_scale_f(slot_in[0], 255.0f);
  const float inv = __fdiv_rn(1.0f, s_in);
  float zmax = 0.f;
  if (spg < NSP) {
    const int n = spg / SP, sp = spg % SP;
    const float* ib = in + n * CI * SP;
    const float* wb2 = wt + cg * COB;
    float acc[COB];
    #pragma unroll
    for (int c = 0; c < COB; c++) acc[c] = 0.f;
    #pragma unroll 4
    for (int ci = 0; ci < CI; ci++) {
      float v = __fmul_rn(rintf(__fmul_rn(ib[ci * SP + sp], inv)), s_in);
      const float* wp = wb2 + ci * CO;
      #pragma unroll
      for (int c = 0; c < COB; c++) acc[c] += v * wp[c];
    }
    #pragma unroll
    for (int c = 0; c < COB; c++) {
      float g = sg[cg * COB + c], bb = sb[cg * COB + c];
      float z = fmaxf(__fadd_rn(__fmul_rn(acc[c], g), bb), 0.f);
      out[(n * CO + cg * COB + c) * SP + sp] = z;
      zmax = fmaxf(zmax, z);
    }
  }
  float bm = block_reduce_max256(zmax);
  if (threadIdx.x == 0) slot_max_update(slot_out, bm);
}

// one block per (n,c): quantize conv46 raw output on read, mean over 28x28.
// Sum of quantized values is integer-exact (784*255 < 2^24); one divide.
__global__ void avgpool_kernel(const float* __restrict__ in, float* __restrict__ out,
                               const float* __restrict__ slot_in, float* slot_out) {
  const float s = p2_scale_f(slot_in[0], 255.0f);
  const float inv = __fdiv_rn(1.0f, s);
  const float* p = in + (size_t)blockIdx.x * 784;
  float sum = 0.f;
  for (int i = threadIdx.x; i < 784; i += 256) sum += qact(p[i], inv, s);
  __shared__ float sm[4];
  #pragma unroll
  for (int off = 32; off; off >>= 1) sum += __shfl_down(sum, off);
  if ((threadIdx.x & 63) == 0) sm[threadIdx.x >> 6] = sum;
  __syncthreads();
  if (threadIdx.x == 0) {
    float tot = (sm[0] + sm[1]) + (sm[2] + sm[3]);
    float m = __fdiv_rn(tot, 784.0f);
    out[blockIdx.x] = m;
    slot_max_update(slot_out, m);
  }
}

// quant(mean) -> fc1 -> relu -> quant -> fc2, all in one 256-thread block.
__global__ void tail_kernel(const float* __restrict__ pooled,
                            const float* __restrict__ fw1, const float* __restrict__ fb1,
                            const float* __restrict__ fw2, const float* __restrict__ fb2,
                            const float* __restrict__ slot_in, float* __restrict__ out) {
  __shared__ float xq[1024];   // [16][64]
  __shared__ float hq[256];    // [16][16]
  __shared__ float s2s;
  const int t = threadIdx.x;
  const float s = p2_scale_f(slot_in[0], 255.0f);
  const float inv = __fdiv_rn(1.0f, s);
  for (int i = t; i < 1024; i += 256) xq[i] = qact(pooled[i], inv, s);
  __syncthreads();
  // fc1: wt layout [64][16]
  const int n = t >> 4, j = t & 15;
  float acc = 0.f;
  #pragma unroll 8
  for (int k = 0; k < 64; k++) acc += xq[n * 64 + k] * fw1[k * 16 + j];  // exact
  float z = fmaxf(__fadd_rn(acc, fb1[j]), 0.f);
  float bm = block_reduce_max256(z);
  if (t == 0) s2s = p2_scale_f(bm, 255.0f);
  __syncthreads();
  const float s2 = s2s, inv2 = __fdiv_rn(1.0f, s2);
  hq[t] = qact(z, inv2, s2);
  __syncthreads();
  if (t < 160) {   // fc2: wt layout [16][10]
    const int n2 = t / 10, j2 = t % 10;
    float a2 = 0.f;
    #pragma unroll
    for (int k = 0; k < 16; k++) a2 += hq[n2 * 16 + k] * fw2[k * 10 + j2];  // exact
    out[t] = __fadd_rn(a2, fb2[j2]);
  }
}

extern "C" void kernel_launch(void* const* d_in, const int* in_sizes, int n_in,
                              void* d_out, int out_size, void* d_ws, size_t ws_size,
                              hipStream_t stream) {
  static const int cfg[NL][3] = {   // ci, co, k (pool implied by layer index)
    {3, 32, 3}, {32, 16, 3}, {16, 16, 1}, {16, 32, 3}, {32, 32, 1}, {32, 64, 3},
    {64, 32, 1}, {32, 64, 3}, {64, 32, 1}, {32, 64, 3}, {64, 32, 1}, {32, 64, 3}};

  float* ws = (float*)d_ws;
  float* slots = ws;                 // slots[0..13]
  size_t off = 32;

  float* wq[NL]; float* sgq[NL]; float* sbq[NL];
  for (int l = 0; l < NL; l++) {
    int n = cfg[l][1] * cfg[l][0] * cfg[l][2] * cfg[l][2];
    wq[l] = ws + off; off += (size_t)((n + 15) & ~15);
  }
  for (int l = 0; l < NL; l++) { sgq[l] = ws + off; off += 64; }
  for (int l = 0; l < NL; l++) { sbq[l] = ws + off; off += 64; }
  float* fw1q = ws + off; off += 1024;
  float* fb1q = ws + off; off += 16;
  float* fw2q = ws + off; off += 160;
  float* fb2q = ws + off; off += 16;
  float* A = ws + off; off += 6422528;   // holds conv1 out (max for A-side)
  float* B = ws + off; off += 1605632;   // holds conv32 out (max for B-side)
  float* P = ws + off; off += 1024;      // avgpool means

  WQArgs wa;
  for (int l = 0; l < NL; l++) {
    wa.in[l]      = (const float*)d_in[1 + 3 * l]; wa.out[l]      = wq[l];
    wa.n[l]       = cfg[l][1] * cfg[l][0] * cfg[l][2] * cfg[l][2];
    wa.tc[l]      = cfg[l][1];
    wa.in[12 + l] = (const float*)d_in[2 + 3 * l]; wa.out[12 + l] = sgq[l];
    wa.n[12 + l]  = cfg[l][1];  wa.tc[12 + l] = 0;
    wa.in[24 + l] = (const float*)d_in[3 + 3 * l]; wa.out[24 + l] = sbq[l];
    wa.n[24 + l]  = cfg[l][1];  wa.tc[24 + l] = 0;
  }
  wa.in[36] = (const float*)d_in[37]; wa.out[36] = fw1q; wa.n[36] = 1024; wa.tc[36] = 16;
  wa.in[37] = (const float*)d_in[38]; wa.out[37] = fb1q; wa.n[37] = 16;   wa.tc[37] = 0;
  wa.in[38] = (const float*)d_in[39]; wa.out[38] = fw2q; wa.n[38] = 160;  wa.tc[38] = 10;
  wa.in[39] = (const float*)d_in[40]; wa.out[39] = fb2q; wa.n[39] = 10;   wa.tc[39] = 0;

  const float* x = (const float*)d_in[0];
  const int nx = 16 * 3 * 224 * 224;

  hipMemsetAsync(slots, 0, 32 * sizeof(float), stream);
  prep_kernel<<<40 + 2048, 256, 0, stream>>>(wa, x, nx, slots + 0);

  // layer launches: grid.x = N*HO*WO/256 (exact), grid.y = Co/COB
  conv3x3_pool_t<3, 224, 32, 8><<<dim3(784, 4), 256, 0, stream>>>(
      x, wq[0], sgq[0], sbq[0], A, slots + 0, slots + 1);
  conv3x3_pool_t<32, 112, 16, 4><<<dim3(196, 4), 256, 0, stream>>>(
      A, wq[1], sgq[1], sbq[1], B, slots + 1, slots + 2);
  conv1x1_t<16, 56, 16, 4><<<dim3(196, 4), 256, 0, stream>>>(
      B, wq[2], sgq[2], sbq[2], A, slots + 2, slots + 3);
  conv3x3_t<16, 56, 32, 8><<<dim3(196, 4), 256, 0, stream>>>(
      A, wq[3], sgq[3], sbq[3], B, slots + 3, slots + 4);
  conv1x1_t<32, 56, 32, 8><<<dim3(196, 4), 256, 0, stream>>>(
      B, wq[4], sgq[4], sbq[4], A, slots + 4, slots + 5);
  conv3x3_pool_t<32, 56, 64, 4><<<dim3(49, 16), 256, 0, stream>>>(
      A, wq[5], sgq[5], sbq[5], B, slots + 5, slots + 6);
  conv1x1_t<64, 28, 32, 2><<<dim3(49, 16), 256, 0, stream>>>(
      B, wq[6], sgq[6], sbq[6], A, slots + 6, slots + 7);
  conv3x3_t<32, 28, 64, 4><<<dim3(49, 16), 256, 0, stream>>>(
      A, wq[7], sgq[7], sbq[7], B, slots + 7, slots + 8);
  conv1x1_t<64, 28, 32, 2><<<dim3(49, 16), 256, 0, stream>>>(
      B, wq[8], sgq[8], sbq[8], A, slots + 8, slots + 9);
  conv3x3_t<32, 28, 64, 4><<<dim3(49, 16), 256, 0, stream>>>(
      A, wq[9], sgq[9], sbq[9], B, slots + 9, slots + 10);
  conv1x1_t<64, 28, 32, 2><<<dim3(49, 16), 256, 0, stream>>>(
      B, wq[10], sgq[10], sbq[10], A, slots + 10, slots + 11);
  conv3x3_t<32, 28, 64, 4><<<dim3(49, 16), 256, 0, stream>>>(
      A, wq[11], sgq[11], sbq[11], B, slots + 11, slots + 12);

  avgpool_kernel<<<1024, 256, 0, stream>>>(B, P, slots + 12, slots + 13);
  tail_kernel<<<1, 256, 0, stream>>>(P, fw1q, fb1q, fw2q, fb2q, slots + 13,
                                     (float*)d_out);
}

// Round 4
// 402.394 us; speedup vs baseline: 6.7762x; 1.4744x over previous
//
#include <hip/hip_runtime.h>
#include <math.h>

#define NL 12

typedef short v8s __attribute__((ext_vector_type(8)));
typedef float v4f __attribute__((ext_vector_type(4)));

struct PrepArgs {
  const float* in[40];
  void* out[40];
  int n[40];      // input element count
  int mode[40];   // 0 plain f32 fake-quant, 1 transposed f32 fake-quant, 2 conv int-bf16
  int tc[40];     // mode1: minor dim
  int ci[40], kk[40], kp[40], co[40];   // mode2 geometry
};

// power-of-two scale: 2^ceil(log2(max(maxv,1e-8)/levels)); f32 ratio (matches JAX),
// double log2/ceil so ceil lands on the right side of integer boundaries.
__device__ inline float p2_scale_f(float maxv, float levels) {
  float r = __fdiv_rn(fmaxf(maxv, 1e-8f), levels);
  return (float)exp2(ceil(log2((double)r)));
}

// blockDim must be 256. Result valid on thread 0. All threads must reach.
__device__ inline float block_reduce_max256(float v) {
  __shared__ float sm[4];
  #pragma unroll
  for (int off = 32; off; off >>= 1) v = fmaxf(v, __shfl_down(v, off));
  if ((threadIdx.x & 63) == 0) sm[threadIdx.x >> 6] = v;
  __syncthreads();
  if (threadIdx.x == 0) v = fmaxf(fmaxf(sm[0], sm[1]), fmaxf(sm[2], sm[3]));
  return v;
}

// v >= 0; non-negative float bits compare like unsigned. Read-skip cuts atomics.
__device__ inline void slot_max_update(float* slot, float v) {
  volatile unsigned int* su = (volatile unsigned int*)slot;
  unsigned int bits = __float_as_uint(v);
  if (bits > *su) atomicMax((unsigned int*)slot, bits);
}

// integer-valued float -> bf16 bits by truncation (exact for |v| <= 256)
__device__ inline short ibf16(float v) {
  return (short)(__float_as_uint(v) >> 16);
}

// blocks [0,40): per-tensor weight prep. blocks >=40: grid-stride max of x.
__global__ void prep_kernel(PrepArgs a, float* wslot,
                            const float* __restrict__ x, int nx, float* slot0) {
  if (blockIdx.x >= 40) {
    float m = 0.f;
    for (int i = (blockIdx.x - 40) * 256 + threadIdx.x; i < nx;
         i += (gridDim.x - 40) * 256)
      m = fmaxf(m, x[i]);
    float bm = block_reduce_max256(m);
    if (threadIdx.x == 0) slot_max_update(slot0, bm);
    return;
  }
  __shared__ float ssc;
  const int t = blockIdx.x;
  const float* in = a.in[t];
  const int n = a.n[t], mode = a.mode[t];
  float m = 0.f;
  for (int i = threadIdx.x; i < n; i += 256) m = fmaxf(m, fabsf(in[i]));
  float bm = block_reduce_max256(m);
  if (threadIdx.x == 0) {
    ssc = p2_scale_f(bm, 127.0f);
    if (mode == 2) wslot[t] = ssc;
  }
  __syncthreads();
  const float s = ssc;
  if (mode == 2) {
    // conv weight: int codes as bf16, layout [Co][KP], k = khkw*Ci + ci, zero pad
    ushort* o = (ushort*)a.out[t];
    const int CI = a.ci[t], KK = a.kk[t], KP = a.kp[t], CO = a.co[t];
    const int KT = CI * KK;
    for (int i = threadIdx.x; i < CO * KP; i += 256) {
      int co = i / KP, k = i % KP;
      ushort v = 0;
      if (k < KT) {
        int khkw = k / CI, ci = k % CI;
        float q = rintf(__fdiv_rn(in[(co * CI + ci) * KK + khkw], s));
        q = fminf(fmaxf(q, -128.f), 127.f);
        v = (ushort)(__float_as_uint(q) >> 16);   // exact: |q| <= 128
      }
      o[i] = v;
    }
  } else {
    float* o = (float*)a.out[t];
    const int tc = a.tc[t];
    const int nw = (mode == 1) ? n / tc : 1;
    for (int i = threadIdx.x; i < n; i += 256) {
      float q = rintf(__fdiv_rn(in[i], s));
      q = fminf(fmaxf(q, -128.f), 127.f);
      float v = __fmul_rn(q, s);
      if (mode == 1) o[(i % nw) * tc + i / nw] = v;
      else o[i] = v;
    }
  }
}

// ---------- MFMA implicit-GEMM conv ----------
// D[m][co] = sum_k A[m][k]*B[k][co], A = activation int codes (quantized on
// load), B = weight int codes. Accumulation exact (ints < 2^24). Epilogue:
// conv = acc * (s_in*s_w) [exact], y = conv*g + b (mul-then-add), relu,
// optional in-register 2x2 max-pool, store raw f32 NHWC, track global max.

template <int CI, int H, int CO, bool K3, bool POOL>
__global__ __launch_bounds__(256)
void conv_mfma(const float* __restrict__ in, const short* __restrict__ wt,
               const float* __restrict__ sg, const float* __restrict__ sb,
               float* __restrict__ out, const float* __restrict__ slot_in,
               const float* __restrict__ wslotp, float* slot_out) {
  constexpr int W = H;
  constexpr int KT = (K3 ? 9 : 1) * CI;
  constexpr int SLABS = (KT + 31) / 32;
  constexpr int KP = SLABS * 32;
  constexpr int COT = CO / 16;
  constexpr int HO = POOL ? H / 2 : H;
  constexpr int WO = POOL ? W / 2 : W;

  const int lane = threadIdx.x & 63, widx = threadIdx.x >> 6;
  const int quad = lane >> 4, col = lane & 15;
  const float s_in = p2_scale_f(slot_in[0], 255.0f);
  const float inv = __fdiv_rn(1.0f, s_in);   // exact: s_in = 2^e
  const float S = __fmul_rn(s_in, wslotp[0]);
  const int wv = blockIdx.x * 4 + widx;

  int n, h, w, ph = 0, pw = 0;
  if constexpr (POOL) {
    constexpr int PB = (HO / 2) * (WO / 2);
    n = wv / PB; int r = wv % PB;
    ph = r / (WO / 2); pw = r % (WO / 2);
    h = 4 * ph + (col >> 2); w = 4 * pw + (col & 3);   // pre-pool 4x4 patch
  } else {
    int p = wv * 16 + col;
    n = p / (H * W); int r = p % (H * W);
    h = r / W; w = r % W;
  }
  const float* ibase = in + (size_t)n * H * W * CI;

  v4f acc[COT];
  #pragma unroll
  for (int c = 0; c < COT; c++) acc[c] = (v4f){0.f, 0.f, 0.f, 0.f};

  #pragma unroll
  for (int slab = 0; slab < SLABS; slab++) {
    const int kbase = slab * 32 + quad * 8;
    v8s a;
    if constexpr (K3) {
      int khkw = kbase / CI; khkw = min(khkw, 8);
      const int cib = kbase % CI;
      const int kh = khkw / 3, kw = khkw - kh * 3;
      const int hh = h + kh - 1, ww = w + kw - 1;
      const bool valid = (hh >= 0) && (hh < H) && (ww >= 0) && (ww < W) && (kbase < KT);
      const int hc = min(max(hh, 0), H - 1), wc = min(max(ww, 0), W - 1);
      const float* ap = ibase + (size_t)(hc * W + wc) * CI + cib;
      float4 f0 = ((const float4*)ap)[0];
      float4 f1 = ((const float4*)ap)[1];
      float ff[8] = {f0.x, f0.y, f0.z, f0.w, f1.x, f1.y, f1.z, f1.w};
      #pragma unroll
      for (int j = 0; j < 8; j++) {
        float q = rintf(__fmul_rn(ff[j], inv));
        a[j] = valid ? ibf16(q) : (short)0;
      }
    } else {
      const int cib = kbase % CI;   // pad quads (CI=16) alias real data x zero weights
      const float* ap = ibase + (size_t)(h * W + w) * CI + cib;
      float4 f0 = ((const float4*)ap)[0];
      float4 f1 = ((const float4*)ap)[1];
      float ff[8] = {f0.x, f0.y, f0.z, f0.w, f1.x, f1.y, f1.z, f1.w};
      #pragma unroll
      for (int j = 0; j < 8; j++) a[j] = ibf16(rintf(__fmul_rn(ff[j], inv)));
    }
    #pragma unroll
    for (int c = 0; c < COT; c++) {
      v8s b = *(const v8s*)(wt + (size_t)(c * 16 + col) * KP + kbase);
      acc[c] = __builtin_amdgcn_mfma_f32_16x16x32_bf16(a, b, acc[c], 0, 0, 0);
    }
  }

  float zmax = 0.f;
  #pragma unroll
  for (int c = 0; c < COT; c++) {
    const int cog = c * 16 + col;
    const float g = sg[cog], bb = sb[cog];
    float z[4];
    #pragma unroll
    for (int r2 = 0; r2 < 4; r2++) {
      float t = __fmul_rn(acc[c][r2], S);                       // exact
      z[r2] = fmaxf(__fadd_rn(__fmul_rn(t, g), bb), 0.f);       // matches XLA
    }
    if constexpr (POOL) {
      float h0 = fmaxf(z[0], z[1]), h1 = fmaxf(z[2], z[3]);
      float o0 = fmaxf(h0, __shfl_xor(h0, 16));
      float o1 = fmaxf(h1, __shfl_xor(h1, 16));
      zmax = fmaxf(zmax, fmaxf(o0, o1));
      if (!(quad & 1)) {   // quads 0,2 own pooled rows 0,1
        int oh = 2 * ph + (quad >> 1), ow = 2 * pw;
        float* op = out + ((size_t)((n * HO + oh) * WO + ow)) * CO + cog;
        op[0] = o0; op[CO] = o1;
      }
    } else {
      const int pbase = wv * 16 + quad * 4;
      #pragma unroll
      for (int r2 = 0; r2 < 4; r2++) {
        out[(size_t)(pbase + r2) * CO + cog] = z[r2];
        zmax = fmaxf(zmax, z[r2]);
      }
    }
  }
  float bm = block_reduce_max256(zmax);
  if (threadIdx.x == 0) slot_max_update(slot_out, bm);
}

// conv1: NCHW f32 input x[16,3,224,224], Ci=3, K=27 padded to 32 (one slab),
// CO=32, pool 224->112. Per-lane scalar gather + input quantization.
__global__ __launch_bounds__(256)
void conv1_mfma(const float* __restrict__ x, const short* __restrict__ wt,
                const float* __restrict__ sg, const float* __restrict__ sb,
                float* __restrict__ out, const float* __restrict__ slot_in,
                const float* __restrict__ wslotp, float* slot_out) {
  const int lane = threadIdx.x & 63, widx = threadIdx.x >> 6;
  const int quad = lane >> 4, col = lane & 15;
  const float s_in = p2_scale_f(slot_in[0], 255.0f);
  const float inv = __fdiv_rn(1.0f, s_in);
  const float S = __fmul_rn(s_in, wslotp[0]);
  const int wv = blockIdx.x * 4 + widx;
  const int n = wv / 3136, r = wv % 3136;
  const int ph = r / 56, pw = r % 56;
  const int h = 4 * ph + (col >> 2), w = 4 * pw + (col & 3);

  v8s a;
  #pragma unroll
  for (int j = 0; j < 8; j++) {
    int k = quad * 8 + j;
    int kc = min(k, 26);
    int khkw = kc / 3, ci = kc - khkw * 3;
    int kh = khkw / 3, kw = khkw - kh * 3;
    int hh = h + kh - 1, ww = w + kw - 1;
    bool valid = (k < 27) && (hh >= 0) && (hh < 224) && (ww >= 0) && (ww < 224);
    int hc = min(max(hh, 0), 223), wc = min(max(ww, 0), 223);
    float v = x[((n * 3 + ci) * 224 + hc) * 224 + wc];
    float q = rintf(__fmul_rn(v, inv));
    a[j] = valid ? ibf16(q) : (short)0;
  }
  v4f acc[2];
  acc[0] = (v4f){0.f, 0.f, 0.f, 0.f};
  acc[1] = acc[0];
  #pragma unroll
  for (int c = 0; c < 2; c++) {
    v8s b = *(const v8s*)(wt + (size_t)(c * 16 + col) * 32 + quad * 8);
    acc[c] = __builtin_amdgcn_mfma_f32_16x16x32_bf16(a, b, acc[c], 0, 0, 0);
  }
  float zmax = 0.f;
  #pragma unroll
  for (int c = 0; c < 2; c++) {
    const int cog = c * 16 + col;
    const float g = sg[cog], bb = sb[cog];
    float z[4];
    #pragma unroll
    for (int r2 = 0; r2 < 4; r2++) {
      float t = __fmul_rn(acc[c][r2], S);
      z[r2] = fmaxf(__fadd_rn(__fmul_rn(t, g), bb), 0.f);
    }
    float h0 = fmaxf(z[0], z[1]), h1 = fmaxf(z[2], z[3]);
    float o0 = fmaxf(h0, __shfl_xor(h0, 16));
    float o1 = fmaxf(h1, __shfl_xor(h1, 16));
    zmax = fmaxf(zmax, fmaxf(o0, o1));
    if (!(quad & 1)) {
      int oh = 2 * ph + (quad >> 1), ow = 2 * pw;
      float* op = out + ((size_t)((n * 112 + oh) * 112 + ow)) * 32 + cog;
      op[0] = o0; op[32] = o1;
    }
  }
  float bm = block_reduce_max256(zmax);
  if (threadIdx.x == 0) slot_max_update(slot_out, bm);
}

// NHWC avgpool: in [16][784][64] raw; quantize on read, exact sum, one divide.
__global__ void avgpool_kernel(const float* __restrict__ in, float* __restrict__ out,
                               const float* __restrict__ slot_in, float* slot_out) {
  __shared__ float red[256];
  const float s = p2_scale_f(slot_in[0], 255.0f);
  const float inv = __fdiv_rn(1.0f, s);
  const int nn = blockIdx.x, co = threadIdx.x & 63, part = threadIdx.x >> 6;
  const float* p = in + (size_t)nn * 784 * 64;
  float sum = 0.f;
  for (int i = part * 196; i < part * 196 + 196; i++)
    sum += __fmul_rn(rintf(__fmul_rn(p[i * 64 + co], inv)), s);
  red[threadIdx.x] = sum;
  __syncthreads();
  if (threadIdx.x < 64) {
    float tot = (red[co] + red[64 + co]) + (red[128 + co] + red[192 + co]);
    float m = __fdiv_rn(tot, 784.0f);
    out[nn * 64 + co] = m;
    slot_max_update(slot_out, m);
  }
}

// quant(mean) -> fc1 -> relu -> quant -> fc2, one 256-thread block.
__global__ void tail_kernel(const float* __restrict__ pooled,
                            const float* __restrict__ fw1, const float* __restrict__ fb1,
                            const float* __restrict__ fw2, const float* __restrict__ fb2,
                            const float* __restrict__ slot_in, float* __restrict__ out) {
  __shared__ float xq[1024];
  __shared__ float hq[256];
  __shared__ float s2s;
  const int t = threadIdx.x;
  const float s = p2_scale_f(slot_in[0], 255.0f);
  const float inv = __fdiv_rn(1.0f, s);
  for (int i = t; i < 1024; i += 256)
    xq[i] = __fmul_rn(rintf(__fmul_rn(pooled[i], inv)), s);
  __syncthreads();
  const int n = t >> 4, j = t & 15;
  float acc = 0.f;
  #pragma unroll 8
  for (int k = 0; k < 64; k++) acc += xq[n * 64 + k] * fw1[k * 16 + j];  // exact
  float z = fmaxf(__fadd_rn(acc, fb1[j]), 0.f);
  float bm = block_reduce_max256(z);
  if (t == 0) s2s = p2_scale_f(bm, 255.0f);
  __syncthreads();
  const float s2 = s2s, inv2 = __fdiv_rn(1.0f, s2);
  hq[t] = __fmul_rn(rintf(__fmul_rn(z, inv2)), s2);
  __syncthreads();
  if (t < 160) {
    const int n2 = t / 10, j2 = t % 10;
    float a2 = 0.f;
    #pragma unroll
    for (int k = 0; k < 16; k++) a2 += hq[n2 * 16 + k] * fw2[k * 10 + j2];  // exact
    out[t] = __fadd_rn(a2, fb2[j2]);
  }
}

extern "C" void kernel_launch(void* const* d_in, const int* in_sizes, int n_in,
                              void* d_out, int out_size, void* d_ws, size_t ws_size,
                              hipStream_t stream) {
  static const int h_ci[NL] = {3, 32, 16, 16, 32, 32, 64, 32, 64, 32, 64, 32};
  static const int h_co[NL] = {32, 16, 16, 32, 32, 64, 32, 64, 32, 64, 32, 64};
  static const int h_kk[NL] = {9, 9, 1, 9, 1, 9, 1, 9, 1, 9, 1, 9};
  static const int h_kp[NL] = {32, 288, 32, 160, 32, 288, 64, 288, 64, 288, 64, 288};

  float* ws = (float*)d_ws;
  float* slots = ws;                 // [0..13] activation-max slots
  float* wslot = ws + 16;            // [0..11] conv weight scales
  size_t off = 32;

  short* wq[NL];
  for (int l = 0; l < NL; l++) {
    wq[l] = (short*)(ws + off);
    off += (size_t)(h_co[l] * h_kp[l] + 1) / 2;   // shorts -> floats
  }
  float* sgq[NL]; float* sbq[NL];
  for (int l = 0; l < NL; l++) { sgq[l] = ws + off; off += 64; }
  for (int l = 0; l < NL; l++) { sbq[l] = ws + off; off += 64; }
  float* fw1q = ws + off; off += 1024;
  float* fb1q = ws + off; off += 16;
  float* fw2q = ws + off; off += 160;
  float* fb2q = ws + off; off += 16;
  float* A = ws + off; off += 6422528;   // NHWC ping (max: conv1 out 25.7 MB)
  float* B = ws + off; off += 1605632;   // NHWC pong (max: conv32 out 6.4 MB)
  float* P = ws + off; off += 1024;      // pooled means [16][64]

  PrepArgs pa;
  for (int l = 0; l < NL; l++) {
    pa.in[l] = (const float*)d_in[1 + 3 * l]; pa.out[l] = (void*)wq[l];
    pa.n[l] = h_co[l] * h_ci[l] * h_kk[l];
    pa.mode[l] = 2; pa.tc[l] = 0;
    pa.ci[l] = h_ci[l]; pa.kk[l] = h_kk[l]; pa.kp[l] = h_kp[l]; pa.co[l] = h_co[l];
    pa.in[12 + l] = (const float*)d_in[2 + 3 * l]; pa.out[12 + l] = (void*)sgq[l];
    pa.n[12 + l] = h_co[l]; pa.mode[12 + l] = 0; pa.tc[12 + l] = 0;
    pa.ci[12 + l] = pa.kk[12 + l] = pa.kp[12 + l] = pa.co[12 + l] = 0;
    pa.in[24 + l] = (const float*)d_in[3 + 3 * l]; pa.out[24 + l] = (void*)sbq[l];
    pa.n[24 + l] = h_co[l]; pa.mode[24 + l] = 0; pa.tc[24 + l] = 0;
    pa.ci[24 + l] = pa.kk[24 + l] = pa.kp[24 + l] = pa.co[24 + l] = 0;
  }
  pa.in[36] = (const float*)d_in[37]; pa.out[36] = (void*)fw1q;
  pa.n[36] = 1024; pa.mode[36] = 1; pa.tc[36] = 16;
  pa.ci[36] = pa.kk[36] = pa.kp[36] = pa.co[36] = 0;
  pa.in[37] = (const float*)d_in[38]; pa.out[37] = (void*)fb1q;
  pa.n[37] = 16; pa.mode[37] = 0; pa.tc[37] = 0;
  pa.ci[37] = pa.kk[37] = pa.kp[37] = pa.co[37] = 0;
  pa.in[38] = (const float*)d_in[39]; pa.out[38] = (void*)fw2q;
  pa.n[38] = 160; pa.mode[38] = 1; pa.tc[38] = 10;
  pa.ci[38] = pa.kk[38] = pa.kp[38] = pa.co[38] = 0;
  pa.in[39] = (const float*)d_in[40]; pa.out[39] = (void*)fb2q;
  pa.n[39] = 10; pa.mode[39] = 0; pa.tc[39] = 0;
  pa.ci[39] = pa.kk[39] = pa.kp[39] = pa.co[39] = 0;

  const float* x = (const float*)d_in[0];
  const int nx = 16 * 3 * 224 * 224;

  hipMemsetAsync(slots, 0, 16 * sizeof(float), stream);
  prep_kernel<<<40 + 2048, 256, 0, stream>>>(pa, wslot, x, nx, slots + 0);

  conv1_mfma<<<12544, 256, 0, stream>>>(x, wq[0], sgq[0], sbq[0], A,
                                        slots + 0, wslot + 0, slots + 1);
  conv_mfma<32, 112, 16, true, true><<<3136, 256, 0, stream>>>(
      A, wq[1], sgq[1], sbq[1], B, slots + 1, wslot + 1, slots + 2);
  conv_mfma<16, 56, 16, false, false><<<784, 256, 0, stream>>>(
      B, wq[2], sgq[2], sbq[2], A, slots + 2, wslot + 2, slots + 3);
  conv_mfma<16, 56, 32, true, false><<<784, 256, 0, stream>>>(
      A, wq[3], sgq[3], sbq[3], B, slots + 3, wslot + 3, slots + 4);
  conv_mfma<32, 56, 32, false, false><<<784, 256, 0, stream>>>(
      B, wq[4], sgq[4], sbq[4], A, slots + 4, wslot + 4, slots + 5);
  conv_mfma<32, 56, 64, true, true><<<784, 256, 0, stream>>>(
      A, wq[5], sgq[5], sbq[5], B, slots + 5, wslot + 5, slots + 6);
  conv_mfma<64, 28, 32, false, false><<<196, 256, 0, stream>>>(
      B, wq[6], sgq[6], sbq[6], A, slots + 6, wslot + 6, slots + 7);
  conv_mfma<32, 28, 64, true, false><<<196, 256, 0, stream>>>(
      A, wq[7], sgq[7], sbq[7], B, slots + 7, wslot + 7, slots + 8);
  conv_mfma<64, 28, 32, false, false><<<196, 256, 0, stream>>>(
      B, wq[8], sgq[8], sbq[8], A, slots + 8, wslot + 8, slots + 9);
  conv_mfma<32, 28, 64, true, false><<<196, 256, 0, stream>>>(
      A, wq[9], sgq[9], sbq[9], B, slots + 9, wslot + 9, slots + 10);
  conv_mfma<64, 28, 32, false, false><<<196, 256, 0, stream>>>(
      B, wq[10], sgq[10], sbq[10], A, slots + 10, wslot + 10, slots + 11);
  conv_mfma<32, 28, 64, true, false><<<196, 256, 0, stream>>>(
      A, wq[11], sgq[11], sbq[11], B, slots + 11, wslot + 11, slots + 12);

  avgpool_kernel<<<16, 256, 0, stream>>>(B, P, slots + 12, slots + 13);
  tail_kernel<<<1, 256, 0, stream>>>(P, fw1q, fb1q, fw2q, fb2q, slots + 13,
                                     (float*)d_out);
}